// Round 1
// baseline (247.080 us; speedup 1.0000x reference)
//
#include <hip/hip_runtime.h>
#include <hip/hip_bf16.h>

typedef __attribute__((ext_vector_type(8))) short short8;
typedef __attribute__((ext_vector_type(4))) float f32x4;

#define N_TOK 8192
#define D_HALF 64
#define D_FULL 128
#define QBLK 16
#define KT 32
#define KSPLIT 4
#define NTILES ((N_TOK / KSPLIT) / KT)  // 64

// Pass 1: build Q = [mag*cos(phase) | mag*sin(phase)] (bf16, row-major [N][128])
// and Vt = [mag | phase]^T (bf16, [128][N]) so PV B-fragments are contiguous.
__global__ __launch_bounds__(256) void precompute_kernel(
    const float* __restrict__ mag, const float* __restrict__ phase,
    __hip_bfloat16* __restrict__ Q, __hip_bfloat16* __restrict__ Vt)
{
    int idx = blockIdx.x * 256 + threadIdx.x;
    if (idx >= N_TOK * D_HALF) return;
    int n = idx >> 6, d = idx & 63;
    float m = mag[idx], p = phase[idx];
    float s, c;
    sincosf(p, &s, &c);
    Q[(size_t)n * D_FULL + d]          = __float2bfloat16(m * c);
    Q[(size_t)n * D_FULL + D_HALF + d] = __float2bfloat16(m * s);
    Vt[(size_t)d * N_TOK + n]            = __float2bfloat16(m);
    Vt[(size_t)(D_HALF + d) * N_TOK + n] = __float2bfloat16(p);
}

// Pass 2: flash attention. Block = 256 threads = 4 waves; each wave owns the
// same 16 query rows but 1/4 of the keys (K-split); merge via LDS at the end.
__global__ __launch_bounds__(256) void attn_kernel(
    const __hip_bfloat16* __restrict__ Q, const __hip_bfloat16* __restrict__ Vt,
    float* __restrict__ out)
{
    __shared__ __hip_bfloat16 P_lds[KSPLIT][QBLK][48];  // stride 48 -> 96B rows, 16B-aligned reads
    __shared__ float O_lds[KSPLIT][QBLK][D_FULL];
    __shared__ float m_lds[KSPLIT][QBLK];
    __shared__ float s_lds[KSPLIT][QBLK];

    const int tid  = threadIdx.x;
    const int wid  = tid >> 6;
    const int lane = tid & 63;
    const int g    = lane >> 4;   // k-slice group within fragments
    const int lc   = lane & 15;   // row/col index within 16

    const int qbase = blockIdx.x * QBLK;
    const int k0    = wid * (N_TOK / KSPLIT);

    // Q fragments: A[row=lc][k = 8*g + i], 4 slices of K=32 covering D=128
    short8 aq[4];
    {
        const __hip_bfloat16* qp = Q + (size_t)(qbase + lc) * D_FULL + g * 8;
        #pragma unroll
        for (int ks = 0; ks < 4; ++ks)
            aq[ks] = *reinterpret_cast<const short8*>(qp + ks * 32);
    }

    f32x4 acc[8];
    #pragma unroll
    for (int i = 0; i < 8; ++i) acc[i] = (f32x4)(0.0f);
    float mrow[4], srow[4];
    #pragma unroll
    for (int r = 0; r < 4; ++r) { mrow[r] = -3.0e38f; srow[r] = 0.0f; }

    for (int t = 0; t < NTILES; ++t) {
        const int kt = k0 + t * KT;

        // S = Q . K^T for 16x32 score tile (two 16x16 column blocks)
        f32x4 s0 = (f32x4)(0.0f), s1 = (f32x4)(0.0f);
        const __hip_bfloat16* kp0 = Q + (size_t)(kt + lc) * D_FULL + g * 8;
        const __hip_bfloat16* kp1 = kp0 + 16 * D_FULL;
        #pragma unroll
        for (int ks = 0; ks < 4; ++ks) {
            short8 b0 = *reinterpret_cast<const short8*>(kp0 + ks * 32);
            short8 b1 = *reinterpret_cast<const short8*>(kp1 + ks * 32);
            s0 = __builtin_amdgcn_mfma_f32_16x16x32_bf16(aq[ks], b0, s0, 0, 0, 0);
            s1 = __builtin_amdgcn_mfma_f32_16x16x32_bf16(aq[ks], b1, s1, 0, 0, 0);
        }

        // online softmax; lane holds rows 4g+r (r=0..3), col lc
        float tm[4];
        #pragma unroll
        for (int r = 0; r < 4; ++r) tm[r] = fmaxf(s0[r], s1[r]);
        #pragma unroll
        for (int m = 1; m < 16; m <<= 1) {
            #pragma unroll
            for (int r = 0; r < 4; ++r)
                tm[r] = fmaxf(tm[r], __shfl_xor(tm[r], m));
        }
        float p0[4], p1[4], ts[4], sc[4];
        #pragma unroll
        for (int r = 0; r < 4; ++r) {
            float mn = fmaxf(mrow[r], tm[r]);
            sc[r] = __expf(mrow[r] - mn);
            p0[r] = __expf(s0[r] - mn);
            p1[r] = __expf(s1[r] - mn);
            ts[r] = p0[r] + p1[r];
            mrow[r] = mn;
        }
        #pragma unroll
        for (int m = 1; m < 16; m <<= 1) {
            #pragma unroll
            for (int r = 0; r < 4; ++r)
                ts[r] += __shfl_xor(ts[r], m);
        }
        #pragma unroll
        for (int r = 0; r < 4; ++r) srow[r] = srow[r] * sc[r] + ts[r];
        #pragma unroll
        for (int c = 0; c < 8; ++c) {
            #pragma unroll
            for (int r = 0; r < 4; ++r) acc[c][r] *= sc[r];
        }

        // transpose P through LDS: write D-layout, read A-layout
        #pragma unroll
        for (int r = 0; r < 4; ++r) {
            P_lds[wid][4 * g + r][lc]      = __float2bfloat16(p0[r]);
            P_lds[wid][4 * g + r][16 + lc] = __float2bfloat16(p1[r]);
        }
        asm volatile("s_waitcnt lgkmcnt(0)" ::: "memory");
        short8 pa = *reinterpret_cast<const short8*>(&P_lds[wid][lc][8 * g]);

        // O += P . V  (B fragment from Vt: contiguous along keys)
        const __hip_bfloat16* vp = Vt + (size_t)lc * N_TOK + kt + 8 * g;
        #pragma unroll
        for (int dblk = 0; dblk < 8; ++dblk) {
            short8 vb = *reinterpret_cast<const short8*>(vp + (size_t)dblk * 16 * N_TOK);
            acc[dblk] = __builtin_amdgcn_mfma_f32_16x16x32_bf16(pa, vb, acc[dblk], 0, 0, 0);
        }
    }

    // stash per-wave partial state
    #pragma unroll
    for (int dblk = 0; dblk < 8; ++dblk) {
        #pragma unroll
        for (int r = 0; r < 4; ++r)
            O_lds[wid][4 * g + r][dblk * 16 + lc] = acc[dblk][r];
    }
    if (lc == 0) {
        #pragma unroll
        for (int r = 0; r < 4; ++r) {
            m_lds[wid][4 * g + r] = mrow[r];
            s_lds[wid][4 * g + r] = srow[r];
        }
    }
    __syncthreads();

    // merge the 4 K-split partials and write output (mag cols 0-63, phase 64-127)
    for (int i = tid; i < QBLK * D_FULL; i += 256) {
        int q = i >> 7, d = i & 127;
        float M = m_lds[0][q];
        #pragma unroll
        for (int w = 1; w < KSPLIT; ++w) M = fmaxf(M, m_lds[w][q]);
        float S = 0.0f, O = 0.0f;
        #pragma unroll
        for (int w = 0; w < KSPLIT; ++w) {
            float e = __expf(m_lds[w][q] - M);
            S += s_lds[w][q] * e;
            O += O_lds[w][q][d] * e;
        }
        float val = O / S;
        int row = qbase + q;
        if (d < D_HALF) out[(size_t)row * D_HALF + d] = val;
        else            out[(size_t)N_TOK * D_HALF + (size_t)row * D_HALF + (d - D_HALF)] = val;
    }
}

extern "C" void kernel_launch(void* const* d_in, const int* in_sizes, int n_in,
                              void* d_out, int out_size, void* d_ws, size_t ws_size,
                              hipStream_t stream)
{
    const float* mag   = (const float*)d_in[0];
    const float* phase = (const float*)d_in[1];
    float* out = (float*)d_out;

    __hip_bfloat16* Q  = (__hip_bfloat16*)d_ws;                  // 2 MB
    __hip_bfloat16* Vt = Q + (size_t)N_TOK * D_FULL;             // 2 MB

    precompute_kernel<<<(N_TOK * D_HALF + 255) / 256, 256, 0, stream>>>(mag, phase, Q, Vt);
    attn_kernel<<<N_TOK / QBLK, 256, 0, stream>>>(Q, Vt, out);
}

// Round 2
// 169.529 us; speedup vs baseline: 1.4575x; 1.4575x over previous
//
#include <hip/hip_runtime.h>
#include <hip/hip_bf16.h>

typedef __attribute__((ext_vector_type(8))) short short8;
typedef __attribute__((ext_vector_type(4))) float f32x4;

#define N_TOK 8192
#define D_HALF 64
#define D_FULL 128
#define QW 32                     // q rows per wave (2 subtiles of 16)
#define KT 64                     // keys per inner tile
#define KSPL 8                    // waves per block = k-split factor
#define KEYS_PER (N_TOK / KSPL)   // 1024
#define NT (KEYS_PER / KT)        // 16
#define PSTR 72                   // P_lds row stride (elements): 144B, 16B-aligned, odd multiple of 16B

__global__ __launch_bounds__(256) void precompute_kernel(
    const float* __restrict__ mag, const float* __restrict__ phase,
    __hip_bfloat16* __restrict__ Q, __hip_bfloat16* __restrict__ Vt)
{
    int idx = blockIdx.x * 256 + threadIdx.x;
    if (idx >= N_TOK * D_HALF) return;
    int n = idx >> 6, d = idx & 63;
    float m = mag[idx], p = phase[idx];
    float s, c;
    sincosf(p, &s, &c);
    Q[(size_t)n * D_FULL + d]          = __float2bfloat16(m * c);
    Q[(size_t)n * D_FULL + D_HALF + d] = __float2bfloat16(m * s);
    Vt[(size_t)d * N_TOK + n]            = __float2bfloat16(m);
    Vt[(size_t)(D_HALF + d) * N_TOK + n] = __float2bfloat16(p);
}

// 512 threads = 8 waves; each wave: same 32 q rows, 1/8 of the keys.
// Merge via 3-level LDS tree, fully parallel final write.
__global__ __launch_bounds__(512, 2) void attn_kernel(
    const __hip_bfloat16* __restrict__ Q, const __hip_bfloat16* __restrict__ Vt,
    float* __restrict__ out)
{
    // union: P-transpose scratch during main loop, merge buffers afterwards
    __shared__ __align__(16) char smem[66560];
    __hip_bfloat16 (*P_lds)[QW][PSTR] = reinterpret_cast<__hip_bfloat16 (*)[QW][PSTR]>(smem);   // [KSPL][32][72] = 36 KB
    float (*O_lds)[QW][D_FULL] = reinterpret_cast<float (*)[QW][D_FULL]>(smem);                  // [4][32][128] = 64 KB
    float* m_lds = reinterpret_cast<float*>(smem + 65536);        // [4][32]
    float* s_lds = reinterpret_cast<float*>(smem + 65536 + 512);  // [4][32]

    const int tid  = threadIdx.x;
    const int wid  = tid >> 6;
    const int lane = tid & 63;
    const int g    = lane >> 4;
    const int lc   = lane & 15;

    const int qbase = blockIdx.x * QW;
    const int k0    = wid * KEYS_PER;

    // Q fragments for both 16-row subtiles: A[row=lc][k=ks*32+8g+i]
    short8 aq[2][4];
    #pragma unroll
    for (int qs = 0; qs < 2; ++qs) {
        const __hip_bfloat16* qp = Q + (size_t)(qbase + qs * 16 + lc) * D_FULL + g * 8;
        #pragma unroll
        for (int ks = 0; ks < 4; ++ks)
            aq[qs][ks] = *reinterpret_cast<const short8*>(qp + ks * 32);
    }

    f32x4 acc[2][8];
    #pragma unroll
    for (int qs = 0; qs < 2; ++qs)
        #pragma unroll
        for (int i = 0; i < 8; ++i) acc[qs][i] = (f32x4)(0.0f);
    float mrow[2][4], srow[2][4];
    #pragma unroll
    for (int qs = 0; qs < 2; ++qs)
        #pragma unroll
        for (int r = 0; r < 4; ++r) { mrow[qs][r] = -3.0e38f; srow[qs][r] = 0.0f; }

    #pragma unroll 2
    for (int t = 0; t < NT; ++t) {
        const int kt = k0 + t * KT;

        // ---- S = Q.K^T : 32q x 64k as 2 qsub x 4 key-column-blocks ----
        f32x4 st[2][4];
        #pragma unroll
        for (int qs = 0; qs < 2; ++qs)
            #pragma unroll
            for (int col = 0; col < 4; ++col) st[qs][col] = (f32x4)(0.0f);
        #pragma unroll
        for (int col = 0; col < 4; ++col) {
            const __hip_bfloat16* kp = Q + (size_t)(kt + col * 16 + lc) * D_FULL + g * 8;
            #pragma unroll
            for (int ks = 0; ks < 4; ++ks) {
                short8 b = *reinterpret_cast<const short8*>(kp + ks * 32);
                st[0][col] = __builtin_amdgcn_mfma_f32_16x16x32_bf16(aq[0][ks], b, st[0][col], 0, 0, 0);
                st[1][col] = __builtin_amdgcn_mfma_f32_16x16x32_bf16(aq[1][ks], b, st[1][col], 0, 0, 0);
            }
        }

        // ---- online softmax per q-subtile; lane holds rows 4g+r, col lc(+16*colblk) ----
        #pragma unroll
        for (int qs = 0; qs < 2; ++qs) {
            float tm[4];
            #pragma unroll
            for (int r = 0; r < 4; ++r)
                tm[r] = fmaxf(fmaxf(st[qs][0][r], st[qs][1][r]), fmaxf(st[qs][2][r], st[qs][3][r]));
            #pragma unroll
            for (int m = 1; m < 16; m <<= 1) {
                #pragma unroll
                for (int r = 0; r < 4; ++r) tm[r] = fmaxf(tm[r], __shfl_xor(tm[r], m));
            }
            float mn[4], scl[4], ts[4];
            float pv[4][4];
            #pragma unroll
            for (int r = 0; r < 4; ++r) {
                mn[r]  = fmaxf(mrow[qs][r], tm[r]);
                scl[r] = __expf(mrow[qs][r] - mn[r]);
                mrow[qs][r] = mn[r];
            }
            #pragma unroll
            for (int col = 0; col < 4; ++col)
                #pragma unroll
                for (int r = 0; r < 4; ++r)
                    pv[col][r] = __expf(st[qs][col][r] - mn[r]);
            #pragma unroll
            for (int r = 0; r < 4; ++r)
                ts[r] = (pv[0][r] + pv[1][r]) + (pv[2][r] + pv[3][r]);
            #pragma unroll
            for (int m = 1; m < 16; m <<= 1) {
                #pragma unroll
                for (int r = 0; r < 4; ++r) ts[r] += __shfl_xor(ts[r], m);
            }
            #pragma unroll
            for (int r = 0; r < 4; ++r) srow[qs][r] = srow[qs][r] * scl[r] + ts[r];
            #pragma unroll
            for (int dblk = 0; dblk < 8; ++dblk)
                #pragma unroll
                for (int r = 0; r < 4; ++r) acc[qs][dblk][r] *= scl[r];
            // transpose P through LDS (write D-layout)
            #pragma unroll
            for (int col = 0; col < 4; ++col)
                #pragma unroll
                for (int r = 0; r < 4; ++r)
                    P_lds[wid][qs * 16 + 4 * g + r][col * 16 + lc] = __float2bfloat16(pv[col][r]);
        }
        asm volatile("s_waitcnt lgkmcnt(0)" ::: "memory");

        short8 pa[2][2];
        #pragma unroll
        for (int qs = 0; qs < 2; ++qs)
            #pragma unroll
            for (int kk = 0; kk < 2; ++kk)
                pa[qs][kk] = *reinterpret_cast<const short8*>(&P_lds[wid][qs * 16 + lc][kk * 32 + g * 8]);

        // ---- O += P.V ----
        #pragma unroll
        for (int dblk = 0; dblk < 8; ++dblk) {
            const __hip_bfloat16* vp = Vt + (size_t)(dblk * 16 + lc) * N_TOK + kt + g * 8;
            short8 v0 = *reinterpret_cast<const short8*>(vp);
            short8 v1 = *reinterpret_cast<const short8*>(vp + 32);
            acc[0][dblk] = __builtin_amdgcn_mfma_f32_16x16x32_bf16(pa[0][0], v0, acc[0][dblk], 0, 0, 0);
            acc[1][dblk] = __builtin_amdgcn_mfma_f32_16x16x32_bf16(pa[1][0], v0, acc[1][dblk], 0, 0, 0);
            acc[0][dblk] = __builtin_amdgcn_mfma_f32_16x16x32_bf16(pa[0][1], v1, acc[0][dblk], 0, 0, 0);
            acc[1][dblk] = __builtin_amdgcn_mfma_f32_16x16x32_bf16(pa[1][1], v1, acc[1][dblk], 0, 0, 0);
        }
    }

    // ---- 3-level k-split merge tree in LDS ----
    auto store_partial = [&](int slot) {
        #pragma unroll
        for (int qs = 0; qs < 2; ++qs)
            #pragma unroll
            for (int dblk = 0; dblk < 8; ++dblk)
                #pragma unroll
                for (int r = 0; r < 4; ++r)
                    O_lds[slot][qs * 16 + 4 * g + r][dblk * 16 + lc] = acc[qs][dblk][r];
        if (lc == 0) {
            #pragma unroll
            for (int qs = 0; qs < 2; ++qs)
                #pragma unroll
                for (int r = 0; r < 4; ++r) {
                    m_lds[slot * 32 + qs * 16 + 4 * g + r] = mrow[qs][r];
                    s_lds[slot * 32 + qs * 16 + 4 * g + r] = srow[qs][r];
                }
        }
    };
    auto merge_partial = [&](int slot) {
        #pragma unroll
        for (int qs = 0; qs < 2; ++qs)
            #pragma unroll
            for (int r = 0; r < 4; ++r) {
                int row = qs * 16 + 4 * g + r;
                float mb = m_lds[slot * 32 + row], sb = s_lds[slot * 32 + row];
                float M  = fmaxf(mrow[qs][r], mb);
                float ea = __expf(mrow[qs][r] - M), eb = __expf(mb - M);
                srow[qs][r] = srow[qs][r] * ea + sb * eb;
                mrow[qs][r] = M;
                #pragma unroll
                for (int dblk = 0; dblk < 8; ++dblk)
                    acc[qs][dblk][r] = acc[qs][dblk][r] * ea + O_lds[slot][row][dblk * 16 + lc] * eb;
            }
    };

    __syncthreads();                       // main loop done; P_lds region is dead
    if (wid >= 4) store_partial(wid - 4);
    __syncthreads();
    if (wid < 4) merge_partial(wid);
    __syncthreads();
    if (wid == 2 || wid == 3) store_partial(wid - 2);
    __syncthreads();
    if (wid < 2) merge_partial(wid);
    __syncthreads();
    if (wid < 2) store_partial(wid);       // final two partials into slots 0,1
    __syncthreads();

    // ---- final merge + write, all 512 threads ----
    {
        int q  = tid >> 4;                 // 0..31
        int d0 = (tid & 15) * 8;           // 0..120
        float m0 = m_lds[q],      s0 = s_lds[q];
        float m1 = m_lds[32 + q], s1 = s_lds[32 + q];
        float M  = fmaxf(m0, m1);
        float e0 = __expf(m0 - M), e1 = __expf(m1 - M);
        float invS = 1.0f / (s0 * e0 + s1 * e1);
        int row = qbase + q;
        f32x4 v0, v1;
        #pragma unroll
        for (int j = 0; j < 4; ++j) {
            v0[j] = (O_lds[0][q][d0 + j]     * e0 + O_lds[1][q][d0 + j]     * e1) * invS;
            v1[j] = (O_lds[0][q][d0 + 4 + j] * e0 + O_lds[1][q][d0 + 4 + j] * e1) * invS;
        }
        float* dst = (d0 < D_HALF)
            ? out + (size_t)row * D_HALF + d0
            : out + (size_t)N_TOK * D_HALF + (size_t)row * D_HALF + (d0 - D_HALF);
        *reinterpret_cast<f32x4*>(dst)     = v0;
        *reinterpret_cast<f32x4*>(dst + 4) = v1;
    }
}

extern "C" void kernel_launch(void* const* d_in, const int* in_sizes, int n_in,
                              void* d_out, int out_size, void* d_ws, size_t ws_size,
                              hipStream_t stream)
{
    const float* mag   = (const float*)d_in[0];
    const float* phase = (const float*)d_in[1];
    float* out = (float*)d_out;

    __hip_bfloat16* Q  = (__hip_bfloat16*)d_ws;                  // 2 MB
    __hip_bfloat16* Vt = Q + (size_t)N_TOK * D_FULL;             // 2 MB

    precompute_kernel<<<(N_TOK * D_HALF + 255) / 256, 256, 0, stream>>>(mag, phase, Q, Vt);
    attn_kernel<<<N_TOK / QW, 512, 0, stream>>>(Q, Vt, out);
}

// Round 4
// 134.405 us; speedup vs baseline: 1.8383x; 1.2613x over previous
//
#include <hip/hip_runtime.h>
#include <hip/hip_bf16.h>

typedef __attribute__((ext_vector_type(8))) short short8;
typedef __attribute__((ext_vector_type(4))) float f32x4;
typedef __attribute__((ext_vector_type(16))) float f32x16;
typedef __attribute__((ext_vector_type(2))) int int2v;

#define N_TOK 8192
#define D_HALF 64
#define D_FULL 128
#define QW 32                     // q rows per block (one 32-col MFMA tile)
#define KT 64                     // keys per inner iteration
#define KSPL 8                    // waves per block = k-split
#define KEYS_PER (N_TOK / KSPL)   // 1024
#define NT (KEYS_PER / KT)        // 16
#define OSTR 132                  // padded LDS row stride (floats)
#define THR 8.0f

__global__ __launch_bounds__(256) void precompute_kernel(
    const float* __restrict__ mag, const float* __restrict__ phase,
    __hip_bfloat16* __restrict__ Q, __hip_bfloat16* __restrict__ Vt)
{
    int idx = blockIdx.x * 256 + threadIdx.x;
    if (idx >= N_TOK * D_HALF) return;
    int n = idx >> 6, d = idx & 63;
    float m = mag[idx], p = phase[idx];
    float s, c;
    sincosf(p, &s, &c);
    Q[(size_t)n * D_FULL + d]          = __float2bfloat16(m * c);
    Q[(size_t)n * D_FULL + D_HALF + d] = __float2bfloat16(m * s);
    Vt[(size_t)d * N_TOK + n]            = __float2bfloat16(m);
    Vt[(size_t)(D_HALF + d) * N_TOK + n] = __float2bfloat16(p);
}

static __device__ __forceinline__ unsigned bfpair(float lo, float hi)
{
    __hip_bfloat16 l = __float2bfloat16(lo), h = __float2bfloat16(hi);
    unsigned short ul = *reinterpret_cast<unsigned short*>(&l);
    unsigned short uh = *reinterpret_cast<unsigned short*>(&h);
    return (unsigned)ul | ((unsigned)uh << 16);
}

// 512 threads = 8 waves; all waves share the block's 32 q rows, each owns 1/8
// of the keys. Swapped-operand 32x32x16 MFMA: softmax state fully lane-local.
__global__ __launch_bounds__(512, 2) void attn_kernel(
    const __hip_bfloat16* __restrict__ Q, const __hip_bfloat16* __restrict__ Vt,
    float* __restrict__ out)
{
    __shared__ __align__(16) float O_lds[KSPL][QW][OSTR];  // 135168 B
    __shared__ float ms_lds[KSPL][2][QW];                  // 2 KB

    const int tid  = threadIdx.x;
    const int wid  = tid >> 6;
    const int lane = tid & 63;
    const int li   = lane & 31;   // q column (QK^T) / d row (PV)
    const int hi   = lane >> 5;

    const int qbase = blockIdx.x * QW;
    const int k0    = wid * KEYS_PER;

    // Q as B-operand: col = li (q row), k = d = ks*16 + 8*hi + i
    short8 bq[8];
    {
        const __hip_bfloat16* qp = Q + (size_t)(qbase + li) * D_FULL + 8 * hi;
        #pragma unroll
        for (int ks = 0; ks < 8; ++ks)
            bq[ks] = *reinterpret_cast<const short8*>(qp + ks * 16);
    }

    f32x16 acc[4];   // O^T: acc[dblk], col = q = li, row = d-offset
    #pragma unroll
    for (int d = 0; d < 4; ++d) acc[d] = (f32x16)(0.0f);
    float mrow = -3.0e38f, srow = 0.0f;

    for (int t = 0; t < NT; ++t) {
        const int kt = k0 + t * KT;

        // ---- S^T = K . Q : two 32x32 key-subtiles ----
        f32x16 st[2];
        #pragma unroll
        for (int ksub = 0; ksub < 2; ++ksub) {
            st[ksub] = (f32x16)(0.0f);
            const __hip_bfloat16* kp = Q + (size_t)(kt + ksub * 32 + li) * D_FULL + 8 * hi;
            #pragma unroll
            for (int ks = 0; ks < 8; ++ks) {
                short8 kf = *reinterpret_cast<const short8*>(kp + ks * 16);
                st[ksub] = __builtin_amdgcn_mfma_f32_32x32x16_bf16(kf, bq[ks], st[ksub], 0, 0, 0);
            }
        }

        // ---- online softmax, lane-local (q = li; 32 of 64 keys here, rest on lane^32)
        float mx[16];
        #pragma unroll
        for (int r = 0; r < 16; ++r) mx[r] = fmaxf(st[0][r], st[1][r]);
        #pragma unroll
        for (int w = 8; w >= 1; w >>= 1)
            #pragma unroll
            for (int r = 0; r < w; ++r) mx[r] = fmaxf(mx[r], mx[r + w]);
        float pmax = fmaxf(mx[0], __shfl_xor(mx[0], 32));

        if (!__all(pmax - mrow <= THR)) {          // defer-max: rarely taken
            float mn  = fmaxf(mrow, pmax);
            float scl = __expf(mrow - mn);
            srow *= scl;
            #pragma unroll
            for (int d = 0; d < 4; ++d)
                #pragma unroll
                for (int r = 0; r < 16; ++r) acc[d][r] *= scl;
            mrow = mn;
        }

        #pragma unroll
        for (int ksub = 0; ksub < 2; ++ksub)
            #pragma unroll
            for (int r = 0; r < 16; ++r)
                st[ksub][r] = __expf(st[ksub][r] - mrow);

        float sm[16];
        #pragma unroll
        for (int r = 0; r < 16; ++r) sm[r] = st[0][r] + st[1][r];
        #pragma unroll
        for (int w = 8; w >= 1; w >>= 1)
            #pragma unroll
            for (int r = 0; r < w; ++r) sm[r] += sm[r + w];
        srow += sm[0] + __shfl_xor(sm[0], 32);

        // ---- PV: O^T += V^T . P, P repacked in-register via permlane32_swap ----
        // Packed words per 16-key chunk: a0=(0,1)+4hi, a1=(2,3)+4hi,
        // b0=(8,9)+4hi, b1=(10,11)+4hi (chunk-local keys, col q=li).
        // Need u.w[j] = keys (8hi+2j, 8hi+2j+1):
        //   u.w[0]={a0.lo,b0.lo}, u.w[2]={a0.hi,b0.hi}  -> swap(dst=a0, src=b0)
        //   u.w[1]={a1.lo,b1.lo}, u.w[3]={a1.hi,b1.hi}  -> swap(dst=a1, src=b1)
        #pragma unroll
        for (int c = 0; c < 4; ++c) {
            const f32x16& P = st[c >> 1];
            const int b = 8 * (c & 1);
            unsigned a0 = bfpair(P[b + 0], P[b + 1]);
            unsigned a1 = bfpair(P[b + 2], P[b + 3]);
            unsigned b0 = bfpair(P[b + 4], P[b + 5]);
            unsigned b1 = bfpair(P[b + 6], P[b + 7]);
            int2v r0 = __builtin_amdgcn_permlane32_swap((int)a0, (int)b0, false, false);
            int2v r1 = __builtin_amdgcn_permlane32_swap((int)a1, (int)b1, false, false);
            union { int w[4]; short8 v; } u;
            u.w[0] = r0[0]; u.w[1] = r1[0]; u.w[2] = r0[1]; u.w[3] = r1[1];

            const __hip_bfloat16* vp = Vt + (size_t)li * N_TOK + kt + c * 16 + 8 * hi;
            #pragma unroll
            for (int d = 0; d < 4; ++d) {
                short8 vf = *reinterpret_cast<const short8*>(vp + (size_t)d * 32 * N_TOK);
                acc[d] = __builtin_amdgcn_mfma_f32_32x32x16_bf16(vf, u.v, acc[d], 0, 0, 0);
            }
        }
    }

    // ---- per-wave partial -> LDS ----
    #pragma unroll
    for (int d = 0; d < 4; ++d)
        #pragma unroll
        for (int rr = 0; rr < 4; ++rr) {
            f32x4 v;
            #pragma unroll
            for (int j = 0; j < 4; ++j) v[j] = acc[d][4 * rr + j];
            *reinterpret_cast<f32x4*>(&O_lds[wid][li][d * 32 + 8 * rr + 4 * hi]) = v;
        }
    if (hi == 0) { ms_lds[wid][0][li] = mrow; ms_lds[wid][1][li] = srow; }
    __syncthreads();

    // ---- 8-way merge + write; thread -> (q, 8 d's) ----
    {
        int q  = tid >> 4;
        int dg = (tid & 15) * 8;
        float M = ms_lds[0][0][q];
        #pragma unroll
        for (int s = 1; s < KSPL; ++s) M = fmaxf(M, ms_lds[s][0][q]);
        float e[KSPL], S = 0.0f;
        #pragma unroll
        for (int s = 0; s < KSPL; ++s) {
            e[s] = __expf(ms_lds[s][0][q] - M);
            S += ms_lds[s][1][q] * e[s];
        }
        float inv = 1.0f / S;
        f32x4 o0 = (f32x4)(0.0f), o1 = (f32x4)(0.0f);
        #pragma unroll
        for (int s = 0; s < KSPL; ++s) {
            f32x4 u0 = *reinterpret_cast<const f32x4*>(&O_lds[s][q][dg]);
            f32x4 u1 = *reinterpret_cast<const f32x4*>(&O_lds[s][q][dg + 4]);
            #pragma unroll
            for (int j = 0; j < 4; ++j) { o0[j] += u0[j] * e[s]; o1[j] += u1[j] * e[s]; }
        }
        #pragma unroll
        for (int j = 0; j < 4; ++j) { o0[j] *= inv; o1[j] *= inv; }
        int row = qbase + q;
        float* dst = (dg < D_HALF)
            ? out + (size_t)row * D_HALF + dg
            : out + (size_t)N_TOK * D_HALF + (size_t)row * D_HALF + (dg - D_HALF);
        *reinterpret_cast<f32x4*>(dst)     = o0;
        *reinterpret_cast<f32x4*>(dst + 4) = o1;
    }
}

extern "C" void kernel_launch(void* const* d_in, const int* in_sizes, int n_in,
                              void* d_out, int out_size, void* d_ws, size_t ws_size,
                              hipStream_t stream)
{
    const float* mag   = (const float*)d_in[0];
    const float* phase = (const float*)d_in[1];
    float* out = (float*)d_out;

    __hip_bfloat16* Q  = (__hip_bfloat16*)d_ws;                  // 2 MB
    __hip_bfloat16* Vt = Q + (size_t)N_TOK * D_FULL;             // 2 MB

    precompute_kernel<<<(N_TOK * D_HALF + 255) / 256, 256, 0, stream>>>(mag, phase, Q, Vt);
    attn_kernel<<<N_TOK / QW, 512, 0, stream>>>(Q, Vt, out);
}